// Round 3
// baseline (204.707 us; speedup 1.0000x reference)
//
#include <hip/hip_runtime.h>
#include <math.h>

#define N_FFT_C   1024
#define HOP       256
#define NBANDS    128
#define T_FRAMES  1001
#define B_BATCH   16
#define NOISE_LEN 256000   // (T-1)*HOP
#define PAD       512

// One block (256 threads) per frame. Stockham autosort radix-2 FFT in LDS.
// Full complex FFT (imag=0) -> symmetric real filter multiply -> complex IFFT
// (conjugate twiddles, 1/N scale) -> Hann window -> atomic overlap-add.
__global__ __launch_bounds__(256) void fn_kernel(
    const float* __restrict__ fb,     // (B, 1, 128, T)
    const float* __restrict__ noise,  // (B, 1, NOISE_LEN)
    float* __restrict__ out)          // (B, 1, NOISE_LEN), pre-zeroed
{
    __shared__ float re0[N_FFT_C], im0[N_FFT_C], re1[N_FFT_C], im1[N_FFT_C];
    __shared__ float twc[512], tws[512];
    __shared__ float bands[NBANDS];

    const int tid = threadIdx.x;
    const int f   = blockIdx.x;
    const int b   = f / T_FRAMES;
    const int t   = f - b * T_FRAMES;

    // twiddle table: w[k] = exp(-2*pi*i*k/1024), k in [0,512)
    for (int k = tid; k < 512; k += 256) {
        float ang = -6.283185307179586f * (float)k * (1.0f / 1024.0f);
        float s_, c_;
        sincosf(ang, &s_, &c_);
        twc[k] = c_; tws[k] = s_;
    }
    // per-frame band gains (stride-T gather)
    if (tid < NBANDS) {
        bands[tid] = fb[(size_t)b * (NBANDS * T_FRAMES) + tid * T_FRAMES + t];
    }
    // frame load: padded[t*HOP + k], padded[p] = 2*noise[p-512]-1 inside, else 0
    const float* nb = noise + (size_t)b * NOISE_LEN;
    for (int k = tid; k < N_FFT_C; k += 256) {
        int g = t * HOP + k - PAD;
        float v = 0.0f;
        if (g >= 0 && g < NOISE_LEN) v = nb[g] * 2.0f - 1.0f;
        re0[k] = v;
        im0[k] = 0.0f;
    }
    __syncthreads();

    float *xr = re0, *xi = im0, *yr = re1, *yi = im1;

    // ---------------- forward FFT (10 Stockham stages) ----------------
    for (int stage = 0; stage < 10; ++stage) {
        const int s = 1 << stage;
        for (int i = tid; i < 512; i += 256) {
            const int q = i & (s - 1);
            const int p = i >> stage;
            const float ar = xr[i],       ai = xi[i];
            const float br = xr[i + 512], bi = xi[i + 512];
            const int o  = 2 * i - q;
            const int kk = p << stage;
            const float wr = twc[kk], wi = tws[kk];
            yr[o] = ar + br;
            yi[o] = ai + bi;
            const float dr = ar - br, di = ai - bi;
            yr[o + s] = dr * wr - di * wi;
            yi[o + s] = dr * wi + di * wr;
        }
        __syncthreads();
        float* tp;
        tp = xr; xr = yr; yr = tp;
        tp = xi; xi = yi; yi = tp;
    }
    // result now in xr/xi (natural order)

    // ---------------- symmetric filter multiply ----------------
    for (int j = tid; j < N_FFT_C; j += 256) {
        const int jm = (j <= 512) ? j : (N_FFT_C - j);
        const float g = (jm == 0) ? 0.0f : bands[(jm - 1) >> 2];
        xr[j] *= g;
        xi[j] *= g;
    }
    __syncthreads();

    // ---------------- inverse FFT (conjugate twiddles) ----------------
    for (int stage = 0; stage < 10; ++stage) {
        const int s = 1 << stage;
        for (int i = tid; i < 512; i += 256) {
            const int q = i & (s - 1);
            const int p = i >> stage;
            const float ar = xr[i],       ai = xi[i];
            const float br = xr[i + 512], bi = xi[i + 512];
            const int o  = 2 * i - q;
            const int kk = p << stage;
            const float wr = twc[kk], wi = -tws[kk];
            yr[o] = ar + br;
            yi[o] = ai + bi;
            const float dr = ar - br, di = ai - bi;
            yr[o + s] = dr * wr - di * wi;
            yi[o + s] = dr * wi + di * wr;
        }
        __syncthreads();
        float* tp;
        tp = xr; xr = yr; yr = tp;
        tp = xi; xi = yi; yi = tp;
    }
    // real part of inverse in xr (scale 1/N applied below)

    // ---------------- window + overlap-add ----------------
    float* ob = out + (size_t)b * NOISE_LEN;
    for (int k = tid; k < N_FFT_C; k += 256) {
        const float yv  = xr[k] * (1.0f / 1024.0f);
        const float ang = 6.283185307179586f * (float)k * (1.0f / 1023.0f);
        const float win = 0.5f * (1.0f - cosf(ang));
        const int pos = t * HOP + k - PAD;
        if (pos >= 0 && pos < NOISE_LEN) {
            atomicAdd(&ob[pos], yv * win);
        }
    }
}

extern "C" void kernel_launch(void* const* d_in, const int* in_sizes, int n_in,
                              void* d_out, int out_size, void* d_ws, size_t ws_size,
                              hipStream_t stream) {
    const float* fb    = (const float*)d_in[0];  // (16,1,128,1001) fp32
    const float* noise = (const float*)d_in[1];  // (16,1,256000)   fp32
    float* out = (float*)d_out;                  // (16,1,256000)   fp32

    // harness poisons d_out with 0xAA before every launch -> zero it
    hipMemsetAsync(out, 0, (size_t)out_size * sizeof(float), stream);

    const int grid = B_BATCH * T_FRAMES;  // 16016 frames
    fn_kernel<<<grid, 256, 0, stream>>>(fb, noise, out);
}

// Round 4
// 149.686 us; speedup vs baseline: 1.3676x; 1.3676x over previous
//
#include <hip/hip_runtime.h>
#include <math.h>

#define NFFT   1024
#define HOP    256
#define NBANDS 128
#define TFRM   1001
#define BB     16
#define NLEN   256000   // (T-1)*HOP
#define PADL   512
#define NPAIRS 501      // ceil(1001/2); last pair has no frame_b

// ---- init kernel: twiddle table + Hann window into d_ws (rewritten every call) ----
// ws[0..511]    = cos(-2*pi*k/1024)
// ws[512..1023] = sin(-2*pi*k/1024)
// ws[1024..2047]= 0.5*(1-cos(2*pi*k/1023))
__global__ __launch_bounds__(1024) void init_tables(float* __restrict__ ws) {
    const int k = threadIdx.x;
    if (k < 512) {
        float s_, c_;
        sincosf(-6.283185307179586f * (float)k * (1.0f / 1024.0f), &s_, &c_);
        ws[k]       = c_;
        ws[512 + k] = s_;
    }
    ws[1024 + k] = 0.5f * (1.0f - cosf(6.283185307179586f * (float)k * (1.0f / 1023.0f)));
}

// ---- main kernel: one block per FRAME PAIR ----
// Pack frame_a in Re, frame_b in Im -> one forward FFT -> Hermitian unpack +
// per-frame symmetric real filter + repack -> one inverse FFT -> Re=ya, Im=yb
// -> Hann window -> atomic overlap-add of both frames.
__global__ __launch_bounds__(256) void fn_kernel(
    const float* __restrict__ fb,     // (B, 1, 128, T)
    const float* __restrict__ noise,  // (B, 1, NLEN)
    const float* __restrict__ tbl,    // d_ws tables from init_tables
    float* __restrict__ out)          // (B, 1, NLEN), pre-zeroed
{
    __shared__ float re0[NFFT], im0[NFFT], re1[NFFT], im1[NFFT];
    __shared__ float twc[512], tws[512];
    __shared__ float ga[NBANDS], gb[NBANDS];

    const int tid = threadIdx.x;
    const int blk = blockIdx.x;
    const int b   = blk / NPAIRS;
    const int p   = blk - b * NPAIRS;
    const int ta  = 2 * p;
    const bool has_b = (ta + 1) < TFRM;

    // twiddles global -> LDS
    for (int k = tid; k < 512; k += 256) {
        twc[k] = tbl[k];
        tws[k] = tbl[512 + k];
    }
    // band gains for both frames (stride-T gather)
    if (tid < NBANDS) {
        ga[tid] = fb[(size_t)b * (NBANDS * TFRM) + tid * TFRM + ta];
    } else {
        const int band = tid - NBANDS;
        gb[band] = has_b ? fb[(size_t)b * (NBANDS * TFRM) + band * TFRM + ta + 1] : 0.0f;
    }
    // load both frames: Re = frame_a, Im = frame_b (offset by HOP)
    const float* nb = noise + (size_t)b * NLEN;
    const int base = ta * HOP - PADL;
    for (int k = tid; k < NFFT; k += 256) {
        const int g1 = base + k;
        const int g2 = g1 + HOP;
        float va = (g1 >= 0 && g1 < NLEN) ? nb[g1] * 2.0f - 1.0f : 0.0f;
        float vb = (has_b && g2 >= 0 && g2 < NLEN) ? nb[g2] * 2.0f - 1.0f : 0.0f;
        re0[k] = va;
        im0[k] = vb;
    }
    __syncthreads();

    float *xr = re0, *xi = im0, *yr = re1, *yi = im1;

    // ---------------- forward FFT: 10 Stockham radix-2 stages ----------------
#pragma unroll
    for (int stage = 0; stage < 10; ++stage) {
        const int s = 1 << stage;
#pragma unroll
        for (int u = 0; u < 2; ++u) {
            const int i = tid + u * 256;
            const int q = i & (s - 1);
            const int o = 2 * i - q;
            const int kk = (i >> stage) << stage;
            const float ar = xr[i],       ai = xi[i];
            const float br = xr[i + 512], bi = xi[i + 512];
            const float wr = twc[kk], wi = tws[kk];
            yr[o] = ar + br;
            yi[o] = ai + bi;
            const float dr = ar - br, di = ai - bi;
            yr[o + s] = dr * wr - di * wi;
            yi[o + s] = dr * wi + di * wr;
        }
        __syncthreads();
        float* tp;
        tp = xr; xr = yr; yr = tp;
        tp = xi; xi = yi; yi = tp;
    }
    // Z in xr/xi (== re0/im0 after even # of swaps), natural order

    // -------- Hermitian unpack + per-frame filter + repack into yr/yi --------
    // Fa[k] = (Z[k]+conj(Z[N-k]))/2 ; Fb[k] = -i(Z[k]-conj(Z[N-k]))/2
    // W[k]  = ga[k]*Fa[k] + i*gb[k]*Fb[k]  (ga,gb real, symmetric, DC=0)
#pragma unroll
    for (int u = 0; u < 2; ++u) {
        const int k = tid + u * 256;   // 0..511
        if (k == 0) {
            yr[0] = 0.0f;  // DC gain = 0
            yi[0] = 0.0f;
            // Nyquist (k=512): Fa=(zr,0), Fb=(zi,0) -> W = (ga*zr, gb*zi)
            const float gN_a = ga[127], gN_b = gb[127];
            yr[512] = gN_a * xr[512];
            yi[512] = gN_b * xi[512];
        } else {
            const int m = NFFT - k;
            const float zr1 = xr[k], zi1 = xi[k];
            const float zr2 = xr[m], zi2 = xi[m];
            const float Far = 0.5f * (zr1 + zr2), Fai = 0.5f * (zi1 - zi2);
            const float Fbr = 0.5f * (zi1 + zi2), Fbi = 0.5f * (zr2 - zr1);
            const int bi_ = (k - 1) >> 2;
            const float gA = ga[bi_], gB = gb[bi_];
            yr[k] = gA * Far - gB * Fbi;
            yi[k] = gA * Fai + gB * Fbr;
            yr[m] = gA * Far + gB * Fbi;
            yi[m] = gB * Fbr - gA * Fai;
        }
    }
    __syncthreads();
    // W is in re1/im1; run inverse from there
    xr = re1; xi = im1; yr = re0; yi = im0;

    // ---------------- inverse FFT: conjugate twiddles ----------------
#pragma unroll
    for (int stage = 0; stage < 10; ++stage) {
        const int s = 1 << stage;
#pragma unroll
        for (int u = 0; u < 2; ++u) {
            const int i = tid + u * 256;
            const int q = i & (s - 1);
            const int o = 2 * i - q;
            const int kk = (i >> stage) << stage;
            const float ar = xr[i],       ai = xi[i];
            const float br = xr[i + 512], bi = xi[i + 512];
            const float wr = twc[kk], wi = -tws[kk];
            yr[o] = ar + br;
            yi[o] = ai + bi;
            const float dr = ar - br, di = ai - bi;
            yr[o + s] = dr * wr - di * wi;
            yi[o + s] = dr * wi + di * wr;
        }
        __syncthreads();
        float* tp;
        tp = xr; xr = yr; yr = tp;
        tp = xi; xi = yi; yi = tp;
    }
    // ya = Re/N (frame a), yb = Im/N (frame b), in xr/xi

    // ---------------- window + overlap-add (both frames) ----------------
    const float* win = tbl + 1024;
    float* ob = out + (size_t)b * NLEN;
#pragma unroll
    for (int u = 0; u < 4; ++u) {
        const int k = tid + u * 256;
        const float w = win[k] * (1.0f / 1024.0f);
        const float yva = xr[k] * w;
        const float yvb = xi[k] * w;
        const int pa = base + k;
        const int pb = pa + HOP;
        if (pa >= 0 && pa < NLEN) atomicAdd(&ob[pa], yva);
        if (has_b && pb >= 0 && pb < NLEN) atomicAdd(&ob[pb], yvb);
    }
}

extern "C" void kernel_launch(void* const* d_in, const int* in_sizes, int n_in,
                              void* d_out, int out_size, void* d_ws, size_t ws_size,
                              hipStream_t stream) {
    const float* fb    = (const float*)d_in[0];  // (16,1,128,1001) fp32
    const float* noise = (const float*)d_in[1];  // (16,1,256000)   fp32
    float* out = (float*)d_out;                  // (16,1,256000)   fp32
    float* tbl = (float*)d_ws;                   // 2048 floats = 8 KB

    // harness poisons d_out/d_ws with 0xAA before every launch
    hipMemsetAsync(out, 0, (size_t)out_size * sizeof(float), stream);
    init_tables<<<1, 1024, 0, stream>>>(tbl);

    const int grid = BB * NPAIRS;  // 8016 pair-blocks
    fn_kernel<<<grid, 256, 0, stream>>>(fb, noise, tbl, out);
}

// Round 5
// 137.895 us; speedup vs baseline: 1.4845x; 1.0855x over previous
//
#include <hip/hip_runtime.h>
#include <math.h>

#define NFFT   1024
#define HOP    256
#define NBANDS 128
#define TFRM   1001
#define BB     16
#define NLEN   256000   // (T-1)*HOP
#define PADL   512
#define NPAIRS 501      // ceil(1001/2); last pair has no frame_b

// padded LDS index: +1 word every 32 to break radix-4 scatter bank conflicts
#define PIDX(a) ((a) + ((a) >> 5))

// ---- init kernel: tables into d_ws (rewritten every call) ----
// ws[0..511]    = interleaved (cos,sin) of exp(-2*pi*i*k/1024), k in [0,256)
// ws[512..1535] = Hann window * (1/1024):  0.5*(1-cos(2*pi*k/1023))/1024
__global__ __launch_bounds__(1024) void init_tables(float* __restrict__ ws) {
    const int k = threadIdx.x;
    if (k < 256) {
        float s_, c_;
        sincosf(-6.283185307179586f * (float)k * (1.0f / 1024.0f), &s_, &c_);
        ws[2 * k]     = c_;
        ws[2 * k + 1] = s_;
    }
    ws[512 + k] = 0.5f * (1.0f - cosf(6.283185307179586f * (float)k * (1.0f / 1023.0f)))
                  * (1.0f / 1024.0f);
}

// One Stockham radix-4 stage (canonical twiddle-on-input form, natural-order
// output after 5 stages). SGN=-1 forward, +1 inverse (conjugate twiddles, +i).
// Verified by hand vs DFT definition at N=16.
template<int NS, int SGN>
__device__ __forceinline__ void r4stage(const float* __restrict__ xr,
                                        const float* __restrict__ xi,
                                        float* __restrict__ yr,
                                        float* __restrict__ yi,
                                        const float2* __restrict__ tw, int j) {
    const int m = j & (NS - 1);
    const float a0r = xr[PIDX(j)],       a0i = xi[PIDX(j)];
    const float a1r = xr[PIDX(j + 256)], a1i = xi[PIDX(j + 256)];
    const float a2r = xr[PIDX(j + 512)], a2i = xi[PIDX(j + 512)];
    const float a3r = xr[PIDX(j + 768)], a3i = xi[PIDX(j + 768)];
    float v1r, v1i, v2r, v2i, v3r, v3i;
    if constexpr (NS == 1) {
        v1r = a1r; v1i = a1i; v2r = a2r; v2i = a2i; v3r = a3r; v3i = a3i;
    } else {
        const int k1 = m * (256 / NS);
        const float2 w = tw[k1];
        const float wr1 = w.x;
        const float wi1 = (SGN < 0) ? w.y : -w.y;           // conj for inverse
        const float wr2 = wr1 * wr1 - wi1 * wi1, wi2 = 2.0f * wr1 * wi1;
        const float wr3 = wr2 * wr1 - wi2 * wi1, wi3 = wr2 * wi1 + wi2 * wr1;
        v1r = a1r * wr1 - a1i * wi1; v1i = a1r * wi1 + a1i * wr1;
        v2r = a2r * wr2 - a2i * wi2; v2i = a2r * wi2 + a2i * wr2;
        v3r = a3r * wr3 - a3i * wi3; v3i = a3r * wi3 + a3i * wr3;
    }
    const float t0r = a0r + v2r, t0i = a0i + v2i;
    const float t1r = a0r - v2r, t1i = a0i - v2i;
    const float t2r = v1r + v3r, t2i = v1i + v3i;
    const float ur  = v1r - v3r, ui  = v1i - v3i;
    const float t3r = (SGN < 0) ? ui  : -ui;   // -i*u (fwd) / +i*u (inv)
    const float t3i = (SGN < 0) ? -ur : ur;
    const int idxD = ((j & ~(NS - 1)) << 2) + m;
    yr[PIDX(idxD)]           = t0r + t2r;  yi[PIDX(idxD)]           = t0i + t2i;
    yr[PIDX(idxD + NS)]      = t1r + t3r;  yi[PIDX(idxD + NS)]      = t1i + t3i;
    yr[PIDX(idxD + 2 * NS)]  = t0r - t2r;  yi[PIDX(idxD + 2 * NS)]  = t0i - t2i;
    yr[PIDX(idxD + 3 * NS)]  = t1r - t3r;  yi[PIDX(idxD + 3 * NS)]  = t1i - t3i;
}

// ---- main kernel: one block (256 threads) per FRAME PAIR ----
// Pack frame_a in Re, frame_b in Im -> radix-4 forward FFT (5 stages) ->
// Hermitian unpack + per-frame symmetric real filter + repack -> radix-4
// inverse FFT (5 stages) -> Hann window (pre-scaled) -> atomic overlap-add.
__global__ __launch_bounds__(256) void fn_kernel(
    const float* __restrict__ fb,     // (B, 1, 128, T)
    const float* __restrict__ noise,  // (B, 1, NLEN)
    const float* __restrict__ tbl,    // d_ws tables from init_tables
    float* __restrict__ out)          // (B, 1, NLEN), pre-zeroed
{
    __shared__ float re0[1056], im0[1056], re1[1056], im1[1056];
    __shared__ float2 tw[256];
    __shared__ float ga[NBANDS], gb[NBANDS];

    const int tid = threadIdx.x;
    const int blk = blockIdx.x;
    const int b   = blk / NPAIRS;
    const int p   = blk - b * NPAIRS;
    const int ta  = 2 * p;
    const bool has_b = (ta + 1) < TFRM;

    // twiddles global -> LDS (256 float2)
    tw[tid] = ((const float2*)tbl)[tid & 255];
    // band gains for both frames (stride-T gather)
    if (tid < NBANDS) {
        ga[tid] = fb[(size_t)b * (NBANDS * TFRM) + tid * TFRM + ta];
    } else {
        const int band = tid - NBANDS;
        gb[band] = has_b ? fb[(size_t)b * (NBANDS * TFRM) + band * TFRM + ta + 1] : 0.0f;
    }
    // load both frames: Re = frame_a, Im = frame_b (offset by HOP)
    const float* nb = noise + (size_t)b * NLEN;
    const int base = ta * HOP - PADL;
    for (int k = tid; k < NFFT; k += 256) {
        const int g1 = base + k;
        const int g2 = g1 + HOP;
        const float va = (g1 >= 0 && g1 < NLEN) ? nb[g1] * 2.0f - 1.0f : 0.0f;
        const float vb = (has_b && g2 >= 0 && g2 < NLEN) ? nb[g2] * 2.0f - 1.0f : 0.0f;
        re0[PIDX(k)] = va;
        im0[PIDX(k)] = vb;
    }
    __syncthreads();

    // ---------------- forward FFT: 5 radix-4 Stockham stages ----------------
    r4stage<1,   -1>(re0, im0, re1, im1, tw, tid); __syncthreads();
    r4stage<4,   -1>(re1, im1, re0, im0, tw, tid); __syncthreads();
    r4stage<16,  -1>(re0, im0, re1, im1, tw, tid); __syncthreads();
    r4stage<64,  -1>(re1, im1, re0, im0, tw, tid); __syncthreads();
    r4stage<256, -1>(re0, im0, re1, im1, tw, tid); __syncthreads();
    // Z in re1/im1, natural order

    // -------- Hermitian unpack + per-frame filter + repack: re1 -> re0 --------
    // Fa[k] = (Z[k]+conj(Z[N-k]))/2 ; Fb[k] = -i(Z[k]-conj(Z[N-k]))/2
    // W[k]  = ga[k]*Fa[k] + i*gb[k]*Fb[k]  (ga,gb real, symmetric, DC=0)
#pragma unroll
    for (int u = 0; u < 2; ++u) {
        const int k = tid + u * 256;   // 0..511
        if (k == 0) {
            re0[PIDX(0)] = 0.0f;
            im0[PIDX(0)] = 0.0f;
            // Nyquist (k=512): Fa=(zr,0), Fb=(zi,0) -> W = (ga*zr, gb*zi)
            re0[PIDX(512)] = ga[127] * re1[PIDX(512)];
            im0[PIDX(512)] = gb[127] * im1[PIDX(512)];
        } else {
            const int mm = NFFT - k;
            const float zr1 = re1[PIDX(k)],  zi1 = im1[PIDX(k)];
            const float zr2 = re1[PIDX(mm)], zi2 = im1[PIDX(mm)];
            const float Far = 0.5f * (zr1 + zr2), Fai = 0.5f * (zi1 - zi2);
            const float Fbr = 0.5f * (zi1 + zi2), Fbi = 0.5f * (zr2 - zr1);
            const int bi_ = (k - 1) >> 2;
            const float gA = ga[bi_], gB = gb[bi_];
            re0[PIDX(k)]  = gA * Far - gB * Fbi;
            im0[PIDX(k)]  = gA * Fai + gB * Fbr;
            re0[PIDX(mm)] = gA * Far + gB * Fbi;
            im0[PIDX(mm)] = gB * Fbr - gA * Fai;
        }
    }
    __syncthreads();

    // ---------------- inverse FFT: 5 radix-4 stages (conjugate) ----------------
    r4stage<1,   +1>(re0, im0, re1, im1, tw, tid); __syncthreads();
    r4stage<4,   +1>(re1, im1, re0, im0, tw, tid); __syncthreads();
    r4stage<16,  +1>(re0, im0, re1, im1, tw, tid); __syncthreads();
    r4stage<64,  +1>(re1, im1, re0, im0, tw, tid); __syncthreads();
    r4stage<256, +1>(re0, im0, re1, im1, tw, tid); __syncthreads();
    // ya = re1 (frame a), yb = im1 (frame b); 1/N folded into window table

    // ---------------- window + overlap-add (both frames) ----------------
    const float* win = tbl + 512;
    float* ob = out + (size_t)b * NLEN;
#pragma unroll
    for (int u = 0; u < 4; ++u) {
        const int k = tid + u * 256;
        const float w = win[k];
        const float yva = re1[PIDX(k)] * w;
        const float yvb = im1[PIDX(k)] * w;
        const int pa = base + k;
        const int pb = pa + HOP;
        if (pa >= 0 && pa < NLEN) atomicAdd(&ob[pa], yva);
        if (has_b && pb >= 0 && pb < NLEN) atomicAdd(&ob[pb], yvb);
    }
}

extern "C" void kernel_launch(void* const* d_in, const int* in_sizes, int n_in,
                              void* d_out, int out_size, void* d_ws, size_t ws_size,
                              hipStream_t stream) {
    const float* fb    = (const float*)d_in[0];  // (16,1,128,1001) fp32
    const float* noise = (const float*)d_in[1];  // (16,1,256000)   fp32
    float* out = (float*)d_out;                  // (16,1,256000)   fp32
    float* tbl = (float*)d_ws;                   // 1536 floats = 6 KB

    // harness poisons d_out/d_ws with 0xAA before every launch
    hipMemsetAsync(out, 0, (size_t)out_size * sizeof(float), stream);
    init_tables<<<1, 1024, 0, stream>>>(tbl);

    const int grid = BB * NPAIRS;  // 8016 pair-blocks
    fn_kernel<<<grid, 256, 0, stream>>>(fb, noise, tbl, out);
}

// Round 6
// 136.191 us; speedup vs baseline: 1.5031x; 1.0125x over previous
//
#include <hip/hip_runtime.h>
#include <math.h>

#define NFFT   1024
#define HOP    256
#define NBANDS 128
#define TFRM   1001
#define BB     16
#define NLEN   256000   // (T-1)*HOP
#define PADL   512
#define NPAIRS 501      // ceil(1001/2); last pair has no frame_b

// padded LDS index in float2 units: +1 every 16 breaks radix-4 scatter conflicts
#define PX(a) ((a) + ((a) >> 4))

// ---- init kernel: tables into d_ws (rewritten every call) ----
// ws[0..511]    = interleaved (cos,sin) of exp(-2*pi*i*k/1024), k in [0,256)
// ws[512..1535] = Hann window * (1/1024):  0.5*(1-cos(2*pi*k/1023))/1024
__global__ __launch_bounds__(1024) void init_tables(float* __restrict__ ws) {
    const int k = threadIdx.x;
    if (k < 256) {
        float s_, c_;
        sincosf(-6.283185307179586f * (float)k * (1.0f / 1024.0f), &s_, &c_);
        ws[2 * k]     = c_;
        ws[2 * k + 1] = s_;
    }
    ws[512 + k] = 0.5f * (1.0f - cosf(6.283185307179586f * (float)k * (1.0f / 1023.0f)))
                  * (1.0f / 1024.0f);
}

// One Stockham radix-4 stage on float2 (re,im) LDS data.
// SGN=-1 forward, +1 inverse (conjugate twiddles, +i). Reads j,j+256,j+512,j+768;
// writes scattered per Stockham. Verified by hand vs DFT definition at N=16.
template<int NS, int SGN>
__device__ __forceinline__ void r4stage2(const float2* __restrict__ x,
                                         float2* __restrict__ y,
                                         const float2* __restrict__ tw, int j) {
    const int m = j & (NS - 1);
    const float2 a0 = x[PX(j)];
    const float2 a1 = x[PX(j + 256)];
    const float2 a2 = x[PX(j + 512)];
    const float2 a3 = x[PX(j + 768)];
    float v1r, v1i, v2r, v2i, v3r, v3i;
    {
        const float2 w = tw[m * (256 / NS)];
        const float wr1 = w.x, wi1 = (SGN < 0) ? w.y : -w.y;
        const float wr2 = wr1 * wr1 - wi1 * wi1, wi2 = 2.0f * wr1 * wi1;
        const float wr3 = wr2 * wr1 - wi2 * wi1, wi3 = wr2 * wi1 + wi2 * wr1;
        v1r = a1.x * wr1 - a1.y * wi1; v1i = a1.x * wi1 + a1.y * wr1;
        v2r = a2.x * wr2 - a2.y * wi2; v2i = a2.x * wi2 + a2.y * wr2;
        v3r = a3.x * wr3 - a3.y * wi3; v3i = a3.x * wi3 + a3.y * wr3;
    }
    const float t0r = a0.x + v2r, t0i = a0.y + v2i;
    const float t1r = a0.x - v2r, t1i = a0.y - v2i;
    const float t2r = v1r + v3r,  t2i = v1i + v3i;
    const float ur  = v1r - v3r,  ui  = v1i - v3i;
    const float t3r = (SGN < 0) ? ui  : -ui;
    const float t3i = (SGN < 0) ? -ur : ur;
    const int d = ((j & ~(NS - 1)) << 2) + m;
    y[PX(d)]          = make_float2(t0r + t2r, t0i + t2i);
    y[PX(d + NS)]     = make_float2(t1r + t3r, t1i + t3i);
    y[PX(d + 2*NS)]   = make_float2(t0r - t2r, t0i - t2i);
    y[PX(d + 3*NS)]   = make_float2(t1r - t3r, t1i - t3i);
}

// ---- main kernel: one block (256 threads) per FRAME PAIR ----
// frame_a in Re, frame_b in Im. Fused: global load+fwd stage0; Hermitian
// filter+inv stage0; inv stage NS=256+window+atomic OLA. 9 barriers total.
__global__ __launch_bounds__(256) void fn_kernel(
    const float* __restrict__ fb,     // (B, 1, 128, T)
    const float* __restrict__ noise,  // (B, 1, NLEN)
    const float* __restrict__ tbl,    // d_ws tables from init_tables
    float* __restrict__ out)          // (B, 1, NLEN), pre-zeroed
{
    __shared__ float2 b0[1087], b1[1087];   // PX(1023)=1086
    __shared__ float2 tw[256];
    __shared__ float2 gab[128];             // (ga, gb) per band

    const int tid = threadIdx.x;
    const int blk = blockIdx.x;
    const int b   = blk / NPAIRS;
    const int p   = blk - b * NPAIRS;
    const int ta  = 2 * p;
    const bool has_b = (ta + 1) < TFRM;

    // twiddles global -> LDS
    tw[tid] = ((const float2*)tbl)[tid & 255];
    // band gains for both frames; adjacent in fb so one thread grabs both
    if (tid < NBANDS) {
        const size_t off = (size_t)b * (NBANDS * TFRM) + (size_t)tid * TFRM + ta;
        const float ga_ = fb[off];
        const float gb_ = has_b ? fb[off + 1] : 0.0f;
        gab[tid] = make_float2(ga_, gb_);
    }

    // ---- fused global load + forward stage 0 (NS=1, no twiddle) ----
    const float* nb = noise + (size_t)b * NLEN;
    const int base = ta * HOP - PADL;
    float2 a0, a1, a2, a3;
    {
        const int g = base + tid;
        #define LD2(gg) make_float2( \
            ((gg) >= 0 && (gg) < NLEN) ? nb[(gg)] * 2.0f - 1.0f : 0.0f, \
            (has_b && (gg) + HOP >= 0 && (gg) + HOP < NLEN) ? nb[(gg) + HOP] * 2.0f - 1.0f : 0.0f)
        a0 = LD2(g); a1 = LD2(g + 256); a2 = LD2(g + 512); a3 = LD2(g + 768);
        #undef LD2
        const float t0r = a0.x + a2.x, t0i = a0.y + a2.y;
        const float t1r = a0.x - a2.x, t1i = a0.y - a2.y;
        const float t2r = a1.x + a3.x, t2i = a1.y + a3.y;
        const float ur  = a1.x - a3.x, ui  = a1.y - a3.y;
        const float t3r = ui, t3i = -ur;           // -i*u (forward)
        const int d = 4 * tid;
        b0[PX(d)]     = make_float2(t0r + t2r, t0i + t2i);
        b0[PX(d + 1)] = make_float2(t1r + t3r, t1i + t3i);
        b0[PX(d + 2)] = make_float2(t0r - t2r, t0i - t2i);
        b0[PX(d + 3)] = make_float2(t1r - t3r, t1i - t3i);
    }
    __syncthreads();

    // ---- forward stages NS=4..256 ----
    r4stage2<4,   -1>(b0, b1, tw, tid); __syncthreads();
    r4stage2<16,  -1>(b1, b0, tw, tid); __syncthreads();
    r4stage2<64,  -1>(b0, b1, tw, tid); __syncthreads();
    r4stage2<256, -1>(b1, b0, tw, tid); __syncthreads();
    // Z in b0, natural order

    // ---- fused Hermitian unpack + filter + inverse stage 0 (NS=1) ----
    // W[k] = ga*Fa + i*gb*Fb, Fa=(Z[k]+conj(Z[N-k]))/2, Fb=-i(Z[k]-conj(Z[N-k]))/2
    // General formula covers Nyquist (z2==z1); only k==0 special (DC gain 0).
    {
        float2 W[4];
        #pragma unroll
        for (int c = 0; c < 4; ++c) {
            const int k = tid + 256 * c;
            const float2 z1 = b0[PX(k)];
            const float2 z2 = b0[PX((NFFT - k) & (NFFT - 1))];
            if (k == 0) {
                W[c] = make_float2(0.0f, 0.0f);
            } else {
                const int jm = (k < NFFT - k) ? k : NFFT - k;
                const float2 g = gab[(jm - 1) >> 2];
                const float Far = 0.5f * (z1.x + z2.x), Fai = 0.5f * (z1.y - z2.y);
                const float Fbr = 0.5f * (z1.y + z2.y), Fbi = 0.5f * (z2.x - z1.x);
                W[c] = make_float2(g.x * Far - g.y * Fbi, g.x * Fai + g.y * Fbr);
            }
        }
        __syncthreads();   // done reading b0 before overwriting b1? (b1 is dest; need Z reads done before... b1 unused since fwd NS=64 -- but all threads must finish READING b0 only; writes go to b1 which is free. Barrier still required before next stage reads b1.)
        const float t0r = W[0].x + W[2].x, t0i = W[0].y + W[2].y;
        const float t1r = W[0].x - W[2].x, t1i = W[0].y - W[2].y;
        const float t2r = W[1].x + W[3].x, t2i = W[1].y + W[3].y;
        const float ur  = W[1].x - W[3].x, ui  = W[1].y - W[3].y;
        const float t3r = -ui, t3i = ur;           // +i*u (inverse)
        const int d = 4 * tid;
        b1[PX(d)]     = make_float2(t0r + t2r, t0i + t2i);
        b1[PX(d + 1)] = make_float2(t1r + t3r, t1i + t3i);
        b1[PX(d + 2)] = make_float2(t0r - t2r, t0i - t2i);
        b1[PX(d + 3)] = make_float2(t1r - t3r, t1i - t3i);
    }
    __syncthreads();

    // ---- inverse stages NS=4..64 ----
    r4stage2<4,  +1>(b1, b0, tw, tid); __syncthreads();
    r4stage2<16, +1>(b0, b1, tw, tid); __syncthreads();
    r4stage2<64, +1>(b1, b0, tw, tid); __syncthreads();

    // ---- fused inverse stage NS=256 + window + overlap-add ----
    // outputs land at k = tid, tid+256, tid+512, tid+768 exactly
    {
        const float2 c0 = b0[PX(tid)];
        const float2 c1 = b0[PX(tid + 256)];
        const float2 c2 = b0[PX(tid + 512)];
        const float2 c3 = b0[PX(tid + 768)];
        const float2 w = tw[tid];
        const float wr1 = w.x, wi1 = -w.y;         // conjugate (inverse)
        const float wr2 = wr1 * wr1 - wi1 * wi1, wi2 = 2.0f * wr1 * wi1;
        const float wr3 = wr2 * wr1 - wi2 * wi1, wi3 = wr2 * wi1 + wi2 * wr1;
        const float v1r = c1.x * wr1 - c1.y * wi1, v1i = c1.x * wi1 + c1.y * wr1;
        const float v2r = c2.x * wr2 - c2.y * wi2, v2i = c2.x * wi2 + c2.y * wr2;
        const float v3r = c3.x * wr3 - c3.y * wi3, v3i = c3.x * wi3 + c3.y * wr3;
        const float t0r = c0.x + v2r, t0i = c0.y + v2i;
        const float t1r = c0.x - v2r, t1i = c0.y - v2i;
        const float t2r = v1r + v3r,  t2i = v1i + v3i;
        const float ur  = v1r - v3r,  ui  = v1i - v3i;
        const float t3r = -ui, t3i = ur;           // +i*u (inverse)
        float2 r[4];
        r[0] = make_float2(t0r + t2r, t0i + t2i);
        r[1] = make_float2(t1r + t3r, t1i + t3i);
        r[2] = make_float2(t0r - t2r, t0i - t2i);
        r[3] = make_float2(t1r - t3r, t1i - t3i);

        const float* win = tbl + 512;
        float* ob = out + (size_t)b * NLEN;
        #pragma unroll
        for (int c = 0; c < 4; ++c) {
            const int k = tid + 256 * c;
            const float wv = win[k];               // Hann * 1/1024 (L1-hot)
            const int pa = base + k;
            const int pb = pa + HOP;
            if (pa >= 0 && pa < NLEN) atomicAdd(&ob[pa], r[c].x * wv);
            if (has_b && pb >= 0 && pb < NLEN) atomicAdd(&ob[pb], r[c].y * wv);
        }
    }
}

extern "C" void kernel_launch(void* const* d_in, const int* in_sizes, int n_in,
                              void* d_out, int out_size, void* d_ws, size_t ws_size,
                              hipStream_t stream) {
    const float* fb    = (const float*)d_in[0];  // (16,1,128,1001) fp32
    const float* noise = (const float*)d_in[1];  // (16,1,256000)   fp32
    float* out = (float*)d_out;                  // (16,1,256000)   fp32
    float* tbl = (float*)d_ws;                   // 1536 floats = 6 KB

    // harness poisons d_out/d_ws with 0xAA before every launch
    hipMemsetAsync(out, 0, (size_t)out_size * sizeof(float), stream);
    init_tables<<<1, 1024, 0, stream>>>(tbl);

    const int grid = BB * NPAIRS;  // 8016 pair-blocks
    fn_kernel<<<grid, 256, 0, stream>>>(fb, noise, tbl, out);
}

// Round 7
// 119.397 us; speedup vs baseline: 1.7145x; 1.1407x over previous
//
#include <hip/hip_runtime.h>
#include <math.h>

#define NFFT   1024
#define HOP    256
#define NBANDS 128
#define TFRM   1001
#define BB     16
#define NLEN   256000   // (T-1)*HOP
#define PADL   512
#define NPAIRS 501      // ceil(1001/2); last pair has no frame_b

// padded LDS index in float2 units: +1 every 16 breaks radix-4 scatter conflicts
#define PX(a) ((a) + ((a) >> 4))

// ---- init kernel: tables into d_ws (rewritten every call) ----
// ws[0..511]    = interleaved (cos,sin) of exp(-2*pi*i*k/1024), k in [0,256)
// ws[512..1535] = Hann window * (1/1024):  0.5*(1-cos(2*pi*k/1023))/1024
__global__ __launch_bounds__(1024) void init_tables(float* __restrict__ ws) {
    const int k = threadIdx.x;
    if (k < 256) {
        float s_, c_;
        sincosf(-6.283185307179586f * (float)k * (1.0f / 1024.0f), &s_, &c_);
        ws[2 * k]     = c_;
        ws[2 * k + 1] = s_;
    }
    ws[512 + k] = 0.5f * (1.0f - cosf(6.283185307179586f * (float)k * (1.0f / 1023.0f)))
                  * (1.0f / 1024.0f);
}

// One Stockham radix-4 stage on float2 (re,im) LDS data.
// SGN=-1 forward, +1 inverse (conjugate twiddles, +i). Reads j,j+256,j+512,j+768;
// writes scattered per Stockham. Verified by hand vs DFT definition at N=16.
template<int NS, int SGN>
__device__ __forceinline__ void r4stage2(const float2* __restrict__ x,
                                         float2* __restrict__ y,
                                         const float2* __restrict__ tw, int j) {
    const int m = j & (NS - 1);
    const float2 a0 = x[PX(j)];
    const float2 a1 = x[PX(j + 256)];
    const float2 a2 = x[PX(j + 512)];
    const float2 a3 = x[PX(j + 768)];
    float v1r, v1i, v2r, v2i, v3r, v3i;
    {
        const float2 w = tw[m * (256 / NS)];
        const float wr1 = w.x, wi1 = (SGN < 0) ? w.y : -w.y;
        const float wr2 = wr1 * wr1 - wi1 * wi1, wi2 = 2.0f * wr1 * wi1;
        const float wr3 = wr2 * wr1 - wi2 * wi1, wi3 = wr2 * wi1 + wi2 * wr1;
        v1r = a1.x * wr1 - a1.y * wi1; v1i = a1.x * wi1 + a1.y * wr1;
        v2r = a2.x * wr2 - a2.y * wi2; v2i = a2.x * wi2 + a2.y * wr2;
        v3r = a3.x * wr3 - a3.y * wi3; v3i = a3.x * wi3 + a3.y * wr3;
    }
    const float t0r = a0.x + v2r, t0i = a0.y + v2i;
    const float t1r = a0.x - v2r, t1i = a0.y - v2i;
    const float t2r = v1r + v3r,  t2i = v1i + v3i;
    const float ur  = v1r - v3r,  ui  = v1i - v3i;
    const float t3r = (SGN < 0) ? ui  : -ui;
    const float t3i = (SGN < 0) ? -ur : ur;
    const int d = ((j & ~(NS - 1)) << 2) + m;
    y[PX(d)]          = make_float2(t0r + t2r, t0i + t2i);
    y[PX(d + NS)]     = make_float2(t1r + t3r, t1i + t3i);
    y[PX(d + 2*NS)]   = make_float2(t0r - t2r, t0i - t2i);
    y[PX(d + 3*NS)]   = make_float2(t1r - t3r, t1i - t3i);
}

// ---- main kernel: one block (256 threads) per FRAME PAIR ----
// frame_a in Re, frame_b in Im. Fused: global load+fwd stage0; Hermitian
// filter+inv stage0; inv stage NS=256+window+register-merged OLA (5 atomics
// per thread instead of 8 -- frame a and b contributions to the same output
// position differ by exactly 256 = one c-step, same thread).
__global__ __launch_bounds__(256) void fn_kernel(
    const float* __restrict__ fb,     // (B, 1, 128, T)
    const float* __restrict__ noise,  // (B, 1, NLEN)
    const float* __restrict__ tbl,    // d_ws tables from init_tables
    float* __restrict__ out)          // (B, 1, NLEN), pre-zeroed
{
    __shared__ float2 b0[1087], b1[1087];   // PX(1023)=1086
    __shared__ float2 tw[256];
    __shared__ float2 gab[128];             // (ga, gb) per band

    const int tid = threadIdx.x;
    const int blk = blockIdx.x;
    const int b   = blk / NPAIRS;
    const int p   = blk - b * NPAIRS;
    const int ta  = 2 * p;
    const bool has_b = (ta + 1) < TFRM;

    // twiddles global -> LDS
    tw[tid] = ((const float2*)tbl)[tid & 255];
    // band gains for both frames; adjacent in fb so one thread grabs both
    if (tid < NBANDS) {
        const size_t off = (size_t)b * (NBANDS * TFRM) + (size_t)tid * TFRM + ta;
        const float ga_ = fb[off];
        const float gb_ = has_b ? fb[off + 1] : 0.0f;
        gab[tid] = make_float2(ga_, gb_);
    }

    // ---- fused global load + forward stage 0 (NS=1, no twiddle) ----
    const float* nb = noise + (size_t)b * NLEN;
    const int base = ta * HOP - PADL;
    float2 a0, a1, a2, a3;
    {
        const int g = base + tid;
        #define LD2(gg) make_float2( \
            ((gg) >= 0 && (gg) < NLEN) ? nb[(gg)] * 2.0f - 1.0f : 0.0f, \
            (has_b && (gg) + HOP >= 0 && (gg) + HOP < NLEN) ? nb[(gg) + HOP] * 2.0f - 1.0f : 0.0f)
        a0 = LD2(g); a1 = LD2(g + 256); a2 = LD2(g + 512); a3 = LD2(g + 768);
        #undef LD2
        const float t0r = a0.x + a2.x, t0i = a0.y + a2.y;
        const float t1r = a0.x - a2.x, t1i = a0.y - a2.y;
        const float t2r = a1.x + a3.x, t2i = a1.y + a3.y;
        const float ur  = a1.x - a3.x, ui  = a1.y - a3.y;
        const float t3r = ui, t3i = -ur;           // -i*u (forward)
        const int d = 4 * tid;
        b0[PX(d)]     = make_float2(t0r + t2r, t0i + t2i);
        b0[PX(d + 1)] = make_float2(t1r + t3r, t1i + t3i);
        b0[PX(d + 2)] = make_float2(t0r - t2r, t0i - t2i);
        b0[PX(d + 3)] = make_float2(t1r - t3r, t1i - t3i);
    }
    __syncthreads();

    // ---- forward stages NS=4..256 ----
    r4stage2<4,   -1>(b0, b1, tw, tid); __syncthreads();
    r4stage2<16,  -1>(b1, b0, tw, tid); __syncthreads();
    r4stage2<64,  -1>(b0, b1, tw, tid); __syncthreads();
    r4stage2<256, -1>(b1, b0, tw, tid); __syncthreads();
    // Z in b0, natural order

    // ---- fused Hermitian unpack + filter + inverse stage 0 (NS=1) ----
    // W[k] = ga*Fa + i*gb*Fb, Fa=(Z[k]+conj(Z[N-k]))/2, Fb=-i(Z[k]-conj(Z[N-k]))/2
    // General formula covers Nyquist (z2==z1); only k==0 special (DC gain 0).
    {
        float2 W[4];
        #pragma unroll
        for (int c = 0; c < 4; ++c) {
            const int k = tid + 256 * c;
            const float2 z1 = b0[PX(k)];
            const float2 z2 = b0[PX((NFFT - k) & (NFFT - 1))];
            if (k == 0) {
                W[c] = make_float2(0.0f, 0.0f);
            } else {
                const int jm = (k < NFFT - k) ? k : NFFT - k;
                const float2 g = gab[(jm - 1) >> 2];
                const float Far = 0.5f * (z1.x + z2.x), Fai = 0.5f * (z1.y - z2.y);
                const float Fbr = 0.5f * (z1.y + z2.y), Fbi = 0.5f * (z2.x - z1.x);
                W[c] = make_float2(g.x * Far - g.y * Fbi, g.x * Fai + g.y * Fbr);
            }
        }
        __syncthreads();   // all reads of b0 complete before b0 is overwritten two stages later; writes below go to b1
        const float t0r = W[0].x + W[2].x, t0i = W[0].y + W[2].y;
        const float t1r = W[0].x - W[2].x, t1i = W[0].y - W[2].y;
        const float t2r = W[1].x + W[3].x, t2i = W[1].y + W[3].y;
        const float ur  = W[1].x - W[3].x, ui  = W[1].y - W[3].y;
        const float t3r = -ui, t3i = ur;           // +i*u (inverse)
        const int d = 4 * tid;
        b1[PX(d)]     = make_float2(t0r + t2r, t0i + t2i);
        b1[PX(d + 1)] = make_float2(t1r + t3r, t1i + t3i);
        b1[PX(d + 2)] = make_float2(t0r - t2r, t0i - t2i);
        b1[PX(d + 3)] = make_float2(t1r - t3r, t1i - t3i);
    }
    __syncthreads();

    // ---- inverse stages NS=4..64 ----
    r4stage2<4,  +1>(b1, b0, tw, tid); __syncthreads();
    r4stage2<16, +1>(b0, b1, tw, tid); __syncthreads();
    r4stage2<64, +1>(b1, b0, tw, tid); __syncthreads();

    // ---- fused inverse stage NS=256 + window + register-merged overlap-add ----
    // outputs land at k = tid, tid+256, tid+512, tid+768 exactly
    {
        const float2 c0 = b0[PX(tid)];
        const float2 c1 = b0[PX(tid + 256)];
        const float2 c2 = b0[PX(tid + 512)];
        const float2 c3 = b0[PX(tid + 768)];
        const float2 w = tw[tid];
        const float wr1 = w.x, wi1 = -w.y;         // conjugate (inverse)
        const float wr2 = wr1 * wr1 - wi1 * wi1, wi2 = 2.0f * wr1 * wi1;
        const float wr3 = wr2 * wr1 - wi2 * wi1, wi3 = wr2 * wi1 + wi2 * wr1;
        const float v1r = c1.x * wr1 - c1.y * wi1, v1i = c1.x * wi1 + c1.y * wr1;
        const float v2r = c2.x * wr2 - c2.y * wi2, v2i = c2.x * wi2 + c2.y * wr2;
        const float v3r = c3.x * wr3 - c3.y * wi3, v3i = c3.x * wi3 + c3.y * wr3;
        const float t0r = c0.x + v2r, t0i = c0.y + v2i;
        const float t1r = c0.x - v2r, t1i = c0.y - v2i;
        const float t2r = v1r + v3r,  t2i = v1i + v3i;
        const float ur  = v1r - v3r,  ui  = v1i - v3i;
        const float t3r = -ui, t3i = ur;           // +i*u (inverse)
        float2 r[4];
        r[0] = make_float2(t0r + t2r, t0i + t2i);
        r[1] = make_float2(t1r + t3r, t1i + t3i);
        r[2] = make_float2(t0r - t2r, t0i - t2i);
        r[3] = make_float2(t1r - t3r, t1i - t3i);

        // windowed values: frame a sample k=tid+256c goes to base+k;
        // frame b sample k goes to base+k+256. Both congruent tid (mod 256)
        // -> this thread owns output slots base+tid+256c, c=0..4. Merge in
        // registers: s[c] = a-part(c) + b-part(c-1). (gb==0 on tail pair
        // makes the b-channel IFFT ~0, so no has_b gate needed.)
        const float* win = tbl + 512;
        float wv[4];
        #pragma unroll
        for (int c = 0; c < 4; ++c) wv[c] = win[tid + 256 * c];
        float s[5];
        s[0] = r[0].x * wv[0];
        s[1] = r[1].x * wv[1] + r[0].y * wv[0];
        s[2] = r[2].x * wv[2] + r[1].y * wv[1];
        s[3] = r[3].x * wv[3] + r[2].y * wv[2];
        s[4] =                  r[3].y * wv[3];

        float* ob = out + (size_t)b * NLEN;
        #pragma unroll
        for (int c = 0; c < 5; ++c) {
            const int pa = base + tid + 256 * c;
            if (pa >= 0 && pa < NLEN) atomicAdd(&ob[pa], s[c]);
        }
    }
}

extern "C" void kernel_launch(void* const* d_in, const int* in_sizes, int n_in,
                              void* d_out, int out_size, void* d_ws, size_t ws_size,
                              hipStream_t stream) {
    const float* fb    = (const float*)d_in[0];  // (16,1,128,1001) fp32
    const float* noise = (const float*)d_in[1];  // (16,1,256000)   fp32
    float* out = (float*)d_out;                  // (16,1,256000)   fp32
    float* tbl = (float*)d_ws;                   // 1536 floats = 6 KB

    // harness poisons d_out/d_ws with 0xAA before every launch
    hipMemsetAsync(out, 0, (size_t)out_size * sizeof(float), stream);
    init_tables<<<1, 1024, 0, stream>>>(tbl);

    const int grid = BB * NPAIRS;  // 8016 pair-blocks
    fn_kernel<<<grid, 256, 0, stream>>>(fb, noise, tbl, out);
}